// Round 5
// baseline (267.560 us; speedup 1.0000x reference)
//
#include <hip/hip_runtime.h>
#include <math.h>

#define BB 2
#define NN 2048
#define HID 896
#define HQ 14
#define HKV 2
#define DD 64
#define QKV_COLS 1152

typedef __bf16 bf16x8 __attribute__((ext_vector_type(8)));
typedef float f32x4 __attribute__((ext_vector_type(4)));

__device__ inline ushort f2bs(float f) {   // fp32 -> bf16 (RNE), finite inputs
  uint u = __builtin_bit_cast(uint, f);
  u += 0x7FFFu + ((u >> 16) & 1u);
  return (ushort)(u >> 16);
}
__device__ inline float bs2f(ushort u) {
  return __builtin_bit_cast(float, (uint)u << 16);
}

__device__ inline void gload16(const ushort* g, ushort* l) {
  __builtin_amdgcn_global_load_lds(
      (const __attribute__((address_space(1))) uint*)g,
      (__attribute__((address_space(3))) uint*)l, 16, 0, 0);
}

// 16-lane reductions on the VALU pipe (DPP), no DS ops.
// steps: quad_perm xor1 (0xB1), quad_perm xor2 (0x4E), row_ror:4, row_ror:8
__device__ inline float dpp_fmax16(float x) {
  int v;
  v = __builtin_amdgcn_update_dpp(0, __builtin_bit_cast(int, x), 0xB1, 0xF, 0xF, true);
  x = fmaxf(x, __builtin_bit_cast(float, v));
  v = __builtin_amdgcn_update_dpp(0, __builtin_bit_cast(int, x), 0x4E, 0xF, 0xF, true);
  x = fmaxf(x, __builtin_bit_cast(float, v));
  v = __builtin_amdgcn_update_dpp(0, __builtin_bit_cast(int, x), 0x124, 0xF, 0xF, true);
  x = fmaxf(x, __builtin_bit_cast(float, v));
  v = __builtin_amdgcn_update_dpp(0, __builtin_bit_cast(int, x), 0x128, 0xF, 0xF, true);
  x = fmaxf(x, __builtin_bit_cast(float, v));
  return x;
}
__device__ inline float dpp_fadd16(float x) {
  int v;
  v = __builtin_amdgcn_update_dpp(0, __builtin_bit_cast(int, x), 0xB1, 0xF, 0xF, true);
  x += __builtin_bit_cast(float, v);
  v = __builtin_amdgcn_update_dpp(0, __builtin_bit_cast(int, x), 0x4E, 0xF, 0xF, true);
  x += __builtin_bit_cast(float, v);
  v = __builtin_amdgcn_update_dpp(0, __builtin_bit_cast(int, x), 0x124, 0xF, 0xF, true);
  x += __builtin_bit_cast(float, v);
  v = __builtin_amdgcn_update_dpp(0, __builtin_bit_cast(int, x), 0x128, 0xF, 0xF, true);
  x += __builtin_bit_cast(float, v);
  return x;
}

// ---------------------------------------------------------------------------
// prep: [0,3584) cast hidden->bf16 | [3584,4592) qkv-w pack | [4592,5376) o-w
// pack | [5376,5888) rope cos/sin table | [5888,5893) bias pack
// ---------------------------------------------------------------------------
__global__ __launch_bounds__(256)
void prep_kernel(const float* __restrict__ hid, const int* __restrict__ pos,
                 const float* __restrict__ qw, const float* __restrict__ kw,
                 const float* __restrict__ vw, const float* __restrict__ ow,
                 const float* __restrict__ qb, const float* __restrict__ kb,
                 const float* __restrict__ vb,
                 ushort* __restrict__ Ah, ushort* __restrict__ WqkvT,
                 ushort* __restrict__ WoT, float2* __restrict__ tab,
                 float* __restrict__ biasQ)
{
  __shared__ float tile[32][33];
  const int blk = blockIdx.x, t = threadIdx.x;
  if (blk < 3584) {
    int i = blk * 256 + t;
    float4 v = ((const float4*)hid)[i];
    ushort4 o;
    o.x = f2bs(v.x); o.y = f2bs(v.y); o.z = f2bs(v.z); o.w = f2bs(v.w);
    ((ushort4*)Ah)[i] = o;
  } else if (blk < 5376) {
    const float* src; int N, n0, drow, k0;
    if (blk < 4592) {
      int idx = blk - 3584;
      int bx = idx % 36; k0 = (idx / 36) * 32;
      if (bx < 28)      { src = qw; N = 896; n0 = bx * 32;        drow = n0; }
      else if (bx < 32) { src = kw; N = 128; n0 = (bx - 28) * 32; drow = 896 + n0; }
      else              { src = vw; N = 128; n0 = (bx - 32) * 32; drow = 1024 + n0; }
    } else {
      int idx = blk - 4592;
      src = ow; N = 896; n0 = (idx % 28) * 32; k0 = (idx / 28) * 32; drow = n0;
    }
    ushort* dst = (blk < 4592) ? WqkvT : WoT;
    const int tx = t & 31, ty = t >> 5;
#pragma unroll
    for (int i = 0; i < 32; i += 8)
      tile[ty + i][tx] = src[(size_t)(k0 + ty + i) * N + n0 + tx];
    __syncthreads();
#pragma unroll
    for (int i = 0; i < 32; i += 8)
      dst[(size_t)(drow + ty + i) * HID + k0 + tx] = f2bs(tile[tx][ty + i]);
  } else if (blk < 5888) {
    int idx = (blk - 5376) * 256 + t;     // 0 .. 131071
    int m = idx >> 5, f = idx & 31;
    float inv = exp2f(-(float)f * (19.9315685693241741f / 32.0f));
    float ang = (float)pos[m] * inv;
    float sv, cv;
    sincosf(ang, &sv, &cv);
    tab[idx] = make_float2(cv, sv);
  } else {
    int i = (blk - 5888) * 256 + t;
    if (i < QKV_COLS)
      biasQ[i] = (i < 896) ? qb[i] : (i < 1024 ? kb[i - 896] : vb[i - 1024]);
  }
}

// ---------------------------------------------------------------------------
// QKV GEMM (64x128 tile, BK=32) with fused bias + RoPE + scatter epilogue.
// grid (9, 64). bx<8: Q/K cols -> rope -> Q[B,HQ,N,D]/K[B,HKV,N,D].
// bx==8: V cols -> LDS transpose -> Vt[B,HKV,D,N].
// ---------------------------------------------------------------------------
__global__ __launch_bounds__(256)
void gemm_qkv_rope(const ushort* __restrict__ A, const ushort* __restrict__ Bt,
                   const float* __restrict__ biasQ, const float2* __restrict__ tab,
                   ushort* __restrict__ Qo, ushort* __restrict__ Ko,
                   ushort* __restrict__ Vto)
{
  __shared__ ushort smem[9216];          // union: staging 6144 | V-transpose 9216
  ushort* As = smem;                     // 64*32
  ushort* Bs = smem + 2048;              // 128*32
  const int bx = blockIdx.x;
  const int n0 = bx * 128;
  const int m0 = blockIdx.y * 64;
  const int t = threadIdx.x;
  const int w = t >> 6, lane = t & 63;
  const int quad = lane >> 4, nn = lane & 15;
  const int wm = (w & 1) * 32, wn = (w >> 1) * 64;

  f32x4 acc[2][4];
#pragma unroll
  for (int i = 0; i < 2; i++)
#pragma unroll
    for (int j = 0; j < 4; j++) acc[i][j] = (f32x4){0.f, 0.f, 0.f, 0.f};

  for (int k0 = 0; k0 < HID; k0 += 32) {
    __syncthreads();
#pragma unroll
    for (int c = 0; c < 3; c++) {
      int ch = w * 3 + c;
      int rr = (lane >> 2), cl = lane & 3;
      if (ch < 4) {
        int r = ch * 16 + rr;
        int cg = cl ^ ((r >> 1) & 3);
        gload16(A + (size_t)(m0 + r) * HID + k0 + cg * 8, &As[r * 32 + cl * 8]);
      } else {
        int r = (ch - 4) * 16 + rr;
        int cg = cl ^ ((r >> 1) & 3);
        gload16(Bt + (size_t)(n0 + r) * HID + k0 + cg * 8, &Bs[r * 32 + cl * 8]);
      }
    }
    __syncthreads();

    bf16x8 aF[2], bF[4];
#pragma unroll
    for (int i = 0; i < 2; i++) {
      int ra = wm + i * 16 + nn;
      aF[i] = *(const bf16x8*)(&As[ra * 32 + (quad ^ ((ra >> 1) & 3)) * 8]);
    }
#pragma unroll
    for (int j = 0; j < 4; j++) {
      int rb = wn + j * 16 + nn;
      bF[j] = *(const bf16x8*)(&Bs[rb * 32 + (quad ^ ((rb >> 1) & 3)) * 8]);
    }
#pragma unroll
    for (int i = 0; i < 2; i++)
#pragma unroll
      for (int j = 0; j < 4; j++)
        acc[i][j] = __builtin_amdgcn_mfma_f32_16x16x32_bf16(aF[i], bF[j], acc[i][j], 0, 0, 0);
  }

  float bv[4];
#pragma unroll
  for (int j = 0; j < 4; j++) bv[j] = biasQ[n0 + wn + j * 16 + nn];

  if (bx < 8) {
    // RoPE + scatter. head index over the 1152 cols: 0..13 Q, 14..15 K.
    const int hglob = (n0 + wn) >> 6;
#pragma unroll
    for (int i = 0; i < 2; i++) {
#pragma unroll
      for (int r = 0; r < 4; r++) {
        int m = m0 + wm + i * 16 + quad * 4 + r;
        int b = m >> 11, n = m & (NN - 1);
        float2 cs0 = tab[m * 32 + nn];
        float2 cs1 = tab[m * 32 + 16 + nn];
        float x0 = acc[i][0][r] + bv[0];
        float x1 = acc[i][1][r] + bv[1];
        float x2 = acc[i][2][r] + bv[2];
        float x3 = acc[i][3][r] + bv[3];
        float y0 = x0 * cs0.x - x2 * cs0.y;
        float y2 = x2 * cs0.x + x0 * cs0.y;
        float y1 = x1 * cs1.x - x3 * cs1.y;
        float y3 = x3 * cs1.x + x1 * cs1.y;
        ushort* dst = (hglob < HQ)
            ? Qo + ((size_t)(b * HQ + hglob) * NN + n) * DD
            : Ko + ((size_t)(b * HKV + (hglob - HQ)) * NN + n) * DD;
        dst[nn]      = f2bs(y0);
        dst[16 + nn] = f2bs(y1);
        dst[32 + nn] = f2bs(y2);
        dst[48 + nn] = f2bs(y3);
      }
    }
  } else {
    // V: bias + transpose via LDS -> Vt[b][kvh][d][n]
    __syncthreads();                      // staging reads done; reuse smem
    const int kvh = wn >> 6;
    ushort* T = smem + kvh * (64 * 72);
#pragma unroll
    for (int j = 0; j < 4; j++) {
      int dd = j * 16 + nn;
      float bvj = bv[j];
#pragma unroll
      for (int i = 0; i < 2; i++) {
        int mloc = wm + i * 16 + quad * 4;
        ushort4 pk;
        pk.x = f2bs(acc[i][j][0] + bvj);
        pk.y = f2bs(acc[i][j][1] + bvj);
        pk.z = f2bs(acc[i][j][2] + bvj);
        pk.w = f2bs(acc[i][j][3] + bvj);
        *(ushort4*)(&T[dd * 72 + mloc]) = pk;
      }
    }
    __syncthreads();
    const int head = t >> 7, dd2 = (t >> 1) & 63, seg = t & 1;
    const int b = m0 >> 11, nbase = (m0 & (NN - 1)) + seg * 32;
    const ushort* src = smem + head * (64 * 72) + dd2 * 72 + seg * 32;
    ushort* d = Vto + ((size_t)(b * HKV + head) * DD + dd2) * NN + nbase;
#pragma unroll
    for (int u = 0; u < 4; u++) ((uint4*)d)[u] = ((const uint4*)src)[u];
  }
}

// ---------------------------------------------------------------------------
// Generic bf16 MFMA GEMM (64x128, BK=32) for the o-projection (fp32 out).
// ---------------------------------------------------------------------------
__global__ __launch_bounds__(256)
void gemm_o(const ushort* __restrict__ A, const ushort* __restrict__ Bt,
            float* __restrict__ out)
{
  const int n0 = blockIdx.x * 128;
  const int m0 = blockIdx.y * 64;
  __shared__ ushort As[64 * 32];
  __shared__ ushort Bs[128 * 32];
  const int t = threadIdx.x;
  const int w = t >> 6, lane = t & 63;
  const int quad = lane >> 4, nn = lane & 15;
  const int wm = (w & 1) * 32, wn = (w >> 1) * 64;

  f32x4 acc[2][4];
#pragma unroll
  for (int i = 0; i < 2; i++)
#pragma unroll
    for (int j = 0; j < 4; j++) acc[i][j] = (f32x4){0.f, 0.f, 0.f, 0.f};

  for (int k0 = 0; k0 < HID; k0 += 32) {
    __syncthreads();
#pragma unroll
    for (int c = 0; c < 3; c++) {
      int ch = w * 3 + c;
      int rr = (lane >> 2), cl = lane & 3;
      if (ch < 4) {
        int r = ch * 16 + rr;
        int cg = cl ^ ((r >> 1) & 3);
        gload16(A + (size_t)(m0 + r) * HID + k0 + cg * 8, &As[r * 32 + cl * 8]);
      } else {
        int r = (ch - 4) * 16 + rr;
        int cg = cl ^ ((r >> 1) & 3);
        gload16(Bt + (size_t)(n0 + r) * HID + k0 + cg * 8, &Bs[r * 32 + cl * 8]);
      }
    }
    __syncthreads();

    bf16x8 aF[2], bF[4];
#pragma unroll
    for (int i = 0; i < 2; i++) {
      int ra = wm + i * 16 + nn;
      aF[i] = *(const bf16x8*)(&As[ra * 32 + (quad ^ ((ra >> 1) & 3)) * 8]);
    }
#pragma unroll
    for (int j = 0; j < 4; j++) {
      int rb = wn + j * 16 + nn;
      bF[j] = *(const bf16x8*)(&Bs[rb * 32 + (quad ^ ((rb >> 1) & 3)) * 8]);
    }
#pragma unroll
    for (int i = 0; i < 2; i++)
#pragma unroll
      for (int j = 0; j < 4; j++)
        acc[i][j] = __builtin_amdgcn_mfma_f32_16x16x32_bf16(aF[i], bF[j], acc[i][j], 0, 0, 0);
  }

#pragma unroll
  for (int j = 0; j < 4; j++) {
    const int col = n0 + wn + j * 16 + nn;
#pragma unroll
    for (int i = 0; i < 2; i++) {
      const int row = m0 + wm + i * 16 + quad * 4;
#pragma unroll
      for (int r = 0; r < 4; r++)
        out[(size_t)(row + r) * HID + col] = acc[i][j][r];
    }
  }
}

// ---------------------------------------------------------------------------
// Split-KV flash attention. grid.x=64: qc=qt*2+c (reversed); chunk = 1024 keys.
// qt<16: nc=1 (direct write). qt>=16: nc=2 -> partials. K staged in LDS
// (double-buffered, 1 barrier/iter); V frags direct from global (L2-resident);
// softmax max-reduce via DPP; per-lane partial l summed once at the end.
// m state tracked in RAW S units (scale 1/8 folded into exp args).
// ---------------------------------------------------------------------------
#define LS 72
__device__ inline void stageK(const ushort* __restrict__ Kb, int j, ushort* dst,
                              int w, int lane) {
  const int srow = lane >> 3, scl = lane & 7;
#pragma unroll
  for (int i = 0; i < 2; i++) {
    int r = (w * 2 + i) * 8 + srow;
    int cg = scl ^ (r & 7);
    gload16(Kb + (size_t)(j * 64 + r) * DD + cg * 8, dst + r * 64 + scl * 8);
  }
}

__global__ __launch_bounds__(256)
void attn_part_kernel(const ushort* __restrict__ Q, const ushort* __restrict__ K,
                      const ushort* __restrict__ Vt, ushort* __restrict__ O,
                      ushort* __restrict__ Opart, float* __restrict__ mpart,
                      float* __restrict__ lpart)
{
  const int qc = (int)gridDim.x - 1 - (int)blockIdx.x;  // heavy blocks first
  const int qt = qc >> 1, c = qc & 1;
  const int nc = (qt < 16) ? 1 : 2;
  if (c >= nc) return;
  const int h = blockIdx.y, b = blockIdx.z;
  const int kvh = h / (HQ / HKV);
  const int q0 = qt * 64;
  const int jlo = c * 16, jhi = min(qt, jlo + 15);

  __shared__ ushort Ks[2][64 * 64];
  __shared__ ushort Ps[4][16 * LS];

  const int t = threadIdx.x;
  const int w = t >> 6, lane = t & 63;
  const int quad = lane >> 4, nn = lane & 15;
  ushort* PsW = Ps[w];

  const ushort* Qrow = Q + ((size_t)(b * HQ + h) * NN + q0 + w * 16 + nn) * DD;
  bf16x8 aQ0 = *(const bf16x8*)(Qrow + quad * 8);
  bf16x8 aQ1 = *(const bf16x8*)(Qrow + 32 + quad * 8);

  const ushort* Kb  = K  + (size_t)(b * HKV + kvh) * NN * DD;
  const ushort* Vtb = Vt + (size_t)(b * HKV + kvh) * DD * NN;

  f32x4 acc[4];
#pragma unroll
  for (int i = 0; i < 4; i++) acc[i] = (f32x4){0.f, 0.f, 0.f, 0.f};
  float mstate[4], lacc[4];
#pragma unroll
  for (int r = 0; r < 4; r++) { mstate[r] = -1e30f; lacc[r] = 0.f; }

  stageK(Kb, jlo, Ks[0], w, lane);
  int cur = 0;

  for (int j = jlo; j <= jhi; j++) {
    __syncthreads();                     // Ks[cur] landed; Ks[cur^1] free
    if (j < jhi) stageK(Kb, j + 1, Ks[cur ^ 1], w, lane);
    const ushort* Kt = Ks[cur];

    // V fragments straight from global (issued early, used after softmax)
    bf16x8 bvf0[4], bvf1[4];
#pragma unroll
    for (int dt = 0; dt < 4; dt++) {
      const ushort* vr = Vtb + (size_t)(dt * 16 + nn) * NN + j * 64;
      bvf0[dt] = *(const bf16x8*)(vr + quad * 8);
      bvf1[dt] = *(const bf16x8*)(vr + 32 + quad * 8);
    }

    const int ctmax = (j == qt) ? w : 3;
    f32x4 sf[4];
#pragma unroll
    for (int ct = 0; ct < 4; ct++) {
      if (ct > ctmax) break;
      int kr = ct * 16 + nn;
      bf16x8 bk0 = *(const bf16x8*)(&Kt[kr * 64 + ((quad ^ (kr & 7)) & 7) * 8]);
      bf16x8 bk1 = *(const bf16x8*)(&Kt[kr * 64 + (((quad + 4) ^ (kr & 7)) & 7) * 8]);
      f32x4 cacc = (f32x4){0.f, 0.f, 0.f, 0.f};
      cacc = __builtin_amdgcn_mfma_f32_16x16x32_bf16(aQ0, bk0, cacc, 0, 0, 0);
      cacc = __builtin_amdgcn_mfma_f32_16x16x32_bf16(aQ1, bk1, cacc, 0, 0, 0);
      sf[ct] = cacc;
    }

    float s[4][4];
#pragma unroll
    for (int ct = 0; ct < 4; ct++) {
#pragma unroll
      for (int r = 0; r < 4; r++) {
        float v = -1e30f;
        if (ct <= ctmax) {
          v = sf[ct][r];
          if (j == qt && (ct * 16 + nn) > (w * 16 + quad * 4 + r)) v = -1e30f;
        }
        s[ct][r] = v;
      }
    }
    float mt[4];
#pragma unroll
    for (int r = 0; r < 4; r++) {
      mt[r] = fmaxf(fmaxf(s[0][r], s[1][r]), fmaxf(s[2][r], s[3][r]));
      mt[r] = dpp_fmax16(mt[r]);
    }
    float alpha[4], lloc[4];
#pragma unroll
    for (int r = 0; r < 4; r++) {
      float mn = fmaxf(mstate[r], mt[r]);
      alpha[r] = __expf((mstate[r] - mn) * 0.125f);
      mstate[r] = mn;
      lloc[r] = 0.f;
    }
#pragma unroll
    for (int ct = 0; ct < 4; ct++)
#pragma unroll
      for (int r = 0; r < 4; r++) {
        float p = __expf((s[ct][r] - mstate[r]) * 0.125f);
        s[ct][r] = p;
        lloc[r] += p;
      }
#pragma unroll
    for (int r = 0; r < 4; r++) lacc[r] = lacc[r] * alpha[r] + lloc[r];
#pragma unroll
    for (int dt = 0; dt < 4; dt++)
#pragma unroll
      for (int r = 0; r < 4; r++) acc[dt][r] *= alpha[r];

#pragma unroll
    for (int ct = 0; ct < 4; ct++)
#pragma unroll
      for (int r = 0; r < 4; r++)
        PsW[(quad * 4 + r) * LS + ct * 16 + nn] = f2bs(s[ct][r]);

    bf16x8 aP0 = *(const bf16x8*)(&PsW[nn * LS + quad * 8]);
    bf16x8 aP1 = *(const bf16x8*)(&PsW[nn * LS + 32 + quad * 8]);
#pragma unroll
    for (int dt = 0; dt < 4; dt++) {
      acc[dt] = __builtin_amdgcn_mfma_f32_16x16x32_bf16(aP0, bvf0[dt], acc[dt], 0, 0, 0);
      acc[dt] = __builtin_amdgcn_mfma_f32_16x16x32_bf16(aP1, bvf1[dt], acc[dt], 0, 0, 0);
    }
    cur ^= 1;
  }

  float ltot[4];
#pragma unroll
  for (int r = 0; r < 4; r++) ltot[r] = dpp_fadd16(lacc[r]);

  const int rowloc = w * 16 + quad * 4;
  if (nc == 1) {
    float linv[4];
#pragma unroll
    for (int r = 0; r < 4; r++) linv[r] = 1.f / (ltot[r] + 1e-8f);
#pragma unroll
    for (int dt = 0; dt < 4; dt++)
#pragma unroll
      for (int r = 0; r < 4; r++)
        O[(size_t)(b * NN + q0 + rowloc + r) * HID + h * DD + dt * 16 + nn] =
            f2bs(acc[dt][r] * linv[r]);
  } else {
    const int p = (b * HQ + h) * 32 + (qt - 16) * 2 + c;
    ushort* Op = Opart + (size_t)p * 4096;
#pragma unroll
    for (int dt = 0; dt < 4; dt++)
#pragma unroll
      for (int r = 0; r < 4; r++)
        Op[(rowloc + r) * 64 + dt * 16 + nn] = f2bs(acc[dt][r]);
    if (nn == 0) {
#pragma unroll
      for (int r = 0; r < 4; r++) {
        mpart[(size_t)p * 64 + rowloc + r] = mstate[r];   // RAW units
        lpart[(size_t)p * 64 + rowloc + r] = ltot[r];
      }
    }
  }
}

// ---------------------------------------------------------------------------
// Reduce: combine the 2 partials for qt in 16..31. grid (16, 14, 2).
// ---------------------------------------------------------------------------
__global__ __launch_bounds__(256)
void attn_reduce_kernel(const ushort* __restrict__ Opart, const float* __restrict__ mpart,
                        const float* __restrict__ lpart, ushort* __restrict__ O)
{
  const int qt = 16 + blockIdx.x;
  const int h = blockIdx.y, b = blockIdx.z;
  const int pb = (b * HQ + h) * 32 + (qt - 16) * 2;
  const int t = threadIdx.x;
  const int row = t >> 2, cg = t & 3;

  float m0v = mpart[(size_t)pb * 64 + row];
  float m1v = mpart[(size_t)(pb + 1) * 64 + row];
  float l0 = lpart[(size_t)pb * 64 + row];
  float l1 = lpart[(size_t)(pb + 1) * 64 + row];
  float M = fmaxf(m0v, m1v);
  float w0 = __expf((m0v - M) * 0.125f);
  float w1 = __expf((m1v - M) * 0.125f);
  float l = l0 * w0 + l1 * w1;
  const float linv = 1.f / (l + 1e-8f);

  const ushort* Op0 = Opart + (size_t)pb * 4096 + row * 64 + cg * 16;
  const ushort* Op1 = Op0 + 4096;
  ushort ov[16];
#pragma unroll
  for (int k = 0; k < 16; k++)
    ov[k] = f2bs((w0 * bs2f(Op0[k]) + w1 * bs2f(Op1[k])) * linv);
  ushort* Od = O + (size_t)(b * NN + qt * 64 + row) * HID + h * DD + cg * 16;
  *(uint4*)(Od) = *(uint4*)(ov);
  *(uint4*)(Od + 8) = *(uint4*)(ov + 8);
}

// ---------------------------------------------------------------------------
extern "C" void kernel_launch(void* const* d_in, const int* in_sizes, int n_in,
                              void* d_out, int out_size, void* d_ws, size_t ws_size,
                              hipStream_t stream)
{
  const float* hid = (const float*)d_in[0];
  const int*   pos = (const int*)  d_in[1];
  const float* qw  = (const float*)d_in[2];
  const float* qb  = (const float*)d_in[3];
  const float* kw  = (const float*)d_in[4];
  const float* kb  = (const float*)d_in[5];
  const float* vw  = (const float*)d_in[6];
  const float* vb  = (const float*)d_in[7];
  const float* ow  = (const float*)d_in[8];
  float* outp = (float*)d_out;

  // ws (ushort units). Opart (32*28*4096 = 3.67M) overlays Ah (dead after gemm).
  ushort* WqkvT = (ushort*)d_ws;                          // 1,032,192
  ushort* WoT   = WqkvT + (size_t)QKV_COLS * HID;         //   802,816
  ushort* Ah    = WoT   + (size_t)HID * HID;              // 3,670,016
  ushort* Qb    = Ah    + (size_t)4096 * HID;             // 3,670,016
  ushort* Kb    = Qb    + (size_t)BB * HQ  * NN * DD;     //   524,288
  ushort* Vtb   = Kb    + (size_t)BB * HKV * NN * DD;     //   524,288
  ushort* Ob    = Vtb   + (size_t)BB * HKV * NN * DD;     // 3,670,016
  float2* tab   = (float2*)(Ob + (size_t)4096 * HID);     // 4096*32 float2
  float*  biasQ = (float*)(tab + (size_t)4096 * 32);      // 1152
  float*  mpart = biasQ + QKV_COLS;                       // 32*28*64
  float*  lpart = mpart + (size_t)32 * 28 * 64;
  ushort* Opart = Ah;                                     // overlay

  prep_kernel<<<dim3(5893), 256, 0, stream>>>(hid, pos, qw, kw, vw, ow, qb, kb, vb,
                                              Ah, WqkvT, WoT, tab, biasQ);
  gemm_qkv_rope<<<dim3(9, 64), 256, 0, stream>>>(Ah, WqkvT, biasQ, tab, Qb, Kb, Vtb);
  attn_part_kernel<<<dim3(64, HQ, BB), 256, 0, stream>>>(Qb, Kb, Vtb, Ob, Opart, mpart, lpart);
  attn_reduce_kernel<<<dim3(16, HQ, BB), 256, 0, stream>>>(Opart, mpart, lpart, Ob);
  gemm_o<<<dim3(HID / 128, 64), 256, 0, stream>>>(Ob, WoT, outp);
}

// Round 6
// 244.213 us; speedup vs baseline: 1.0956x; 1.0956x over previous
//
#include <hip/hip_runtime.h>
#include <math.h>

#define BB 2
#define NN 2048
#define HID 896
#define HQ 14
#define HKV 2
#define DD 64
#define QKV_COLS 1152

typedef __bf16 bf16x8 __attribute__((ext_vector_type(8)));
typedef float f32x4 __attribute__((ext_vector_type(4)));

__device__ inline ushort f2bs(float f) {   // fp32 -> bf16 (RNE), finite inputs
  uint u = __builtin_bit_cast(uint, f);
  u += 0x7FFFu + ((u >> 16) & 1u);
  return (ushort)(u >> 16);
}
__device__ inline float bs2f(ushort u) {
  return __builtin_bit_cast(float, (uint)u << 16);
}

__device__ inline void gload16(const ushort* g, ushort* l) {
  __builtin_amdgcn_global_load_lds(
      (const __attribute__((address_space(1))) uint*)g,
      (__attribute__((address_space(3))) uint*)l, 16, 0, 0);
}

// 16-lane reductions on the VALU pipe (DPP): quad_perm xor1, xor2, row_ror 4/8
__device__ inline float dpp_fmax16(float x) {
  int v;
  v = __builtin_amdgcn_update_dpp(0, __builtin_bit_cast(int, x), 0xB1, 0xF, 0xF, true);
  x = fmaxf(x, __builtin_bit_cast(float, v));
  v = __builtin_amdgcn_update_dpp(0, __builtin_bit_cast(int, x), 0x4E, 0xF, 0xF, true);
  x = fmaxf(x, __builtin_bit_cast(float, v));
  v = __builtin_amdgcn_update_dpp(0, __builtin_bit_cast(int, x), 0x124, 0xF, 0xF, true);
  x = fmaxf(x, __builtin_bit_cast(float, v));
  v = __builtin_amdgcn_update_dpp(0, __builtin_bit_cast(int, x), 0x128, 0xF, 0xF, true);
  x = fmaxf(x, __builtin_bit_cast(float, v));
  return x;
}
__device__ inline float dpp_fadd16(float x) {
  int v;
  v = __builtin_amdgcn_update_dpp(0, __builtin_bit_cast(int, x), 0xB1, 0xF, 0xF, true);
  x += __builtin_bit_cast(float, v);
  v = __builtin_amdgcn_update_dpp(0, __builtin_bit_cast(int, x), 0x4E, 0xF, 0xF, true);
  x += __builtin_bit_cast(float, v);
  v = __builtin_amdgcn_update_dpp(0, __builtin_bit_cast(int, x), 0x124, 0xF, 0xF, true);
  x += __builtin_bit_cast(float, v);
  v = __builtin_amdgcn_update_dpp(0, __builtin_bit_cast(int, x), 0x128, 0xF, 0xF, true);
  x += __builtin_bit_cast(float, v);
  return x;
}

// ---------------------------------------------------------------------------
// prep: [0,3584) cast hidden->bf16 | [3584,4592) qkv-w pack | [4592,5376) o-w
// pack | [5376,5888) rope cos/sin table | [5888,5893) bias pack
// ---------------------------------------------------------------------------
__global__ __launch_bounds__(256)
void prep_kernel(const float* __restrict__ hid, const int* __restrict__ pos,
                 const float* __restrict__ qw, const float* __restrict__ kw,
                 const float* __restrict__ vw, const float* __restrict__ ow,
                 const float* __restrict__ qb, const float* __restrict__ kb,
                 const float* __restrict__ vb,
                 ushort* __restrict__ Ah, ushort* __restrict__ WqkvT,
                 ushort* __restrict__ WoT, float2* __restrict__ tab,
                 float* __restrict__ biasQ)
{
  __shared__ float tile[32][33];
  const int blk = blockIdx.x, t = threadIdx.x;
  if (blk < 3584) {
    int i = blk * 256 + t;
    float4 v = ((const float4*)hid)[i];
    ushort4 o;
    o.x = f2bs(v.x); o.y = f2bs(v.y); o.z = f2bs(v.z); o.w = f2bs(v.w);
    ((ushort4*)Ah)[i] = o;
  } else if (blk < 5376) {
    const float* src; int N, n0, drow, k0;
    if (blk < 4592) {
      int idx = blk - 3584;
      int bx = idx % 36; k0 = (idx / 36) * 32;
      if (bx < 28)      { src = qw; N = 896; n0 = bx * 32;        drow = n0; }
      else if (bx < 32) { src = kw; N = 128; n0 = (bx - 28) * 32; drow = 896 + n0; }
      else              { src = vw; N = 128; n0 = (bx - 32) * 32; drow = 1024 + n0; }
    } else {
      int idx = blk - 4592;
      src = ow; N = 896; n0 = (idx % 28) * 32; k0 = (idx / 28) * 32; drow = n0;
    }
    ushort* dst = (blk < 4592) ? WqkvT : WoT;
    const int tx = t & 31, ty = t >> 5;
#pragma unroll
    for (int i = 0; i < 32; i += 8)
      tile[ty + i][tx] = src[(size_t)(k0 + ty + i) * N + n0 + tx];
    __syncthreads();
#pragma unroll
    for (int i = 0; i < 32; i += 8)
      dst[(size_t)(drow + ty + i) * HID + k0 + tx] = f2bs(tile[tx][ty + i]);
  } else if (blk < 5888) {
    int idx = (blk - 5376) * 256 + t;     // 0 .. 131071
    int m = idx >> 5, f = idx & 31;
    float inv = exp2f(-(float)f * (19.9315685693241741f / 32.0f));
    float ang = (float)pos[m] * inv;
    float sv, cv;
    sincosf(ang, &sv, &cv);
    tab[idx] = make_float2(cv, sv);
  } else {
    int i = (blk - 5888) * 256 + t;
    if (i < QKV_COLS)
      biasQ[i] = (i < 896) ? qb[i] : (i < 1024 ? kb[i - 896] : vb[i - 1024]);
  }
}

// ---------------------------------------------------------------------------
// QKV GEMM (64x128 tile, BK=32) with fused bias + RoPE + scatter epilogue.
// grid (9, 64). bx<8: Q/K cols -> rope -> LDS transpose -> coalesced stores.
// bx==8: V cols -> LDS transpose -> Vt[B,HKV,D,N].
// ---------------------------------------------------------------------------
__global__ __launch_bounds__(256)
void gemm_qkv_rope(const ushort* __restrict__ A, const ushort* __restrict__ Bt,
                   const float* __restrict__ biasQ, const float2* __restrict__ tab,
                   ushort* __restrict__ Qo, ushort* __restrict__ Ko,
                   ushort* __restrict__ Vto)
{
  __shared__ ushort smem[9216];          // staging 6144 | QK-T 8448 | V-T 9216
  ushort* As = smem;                     // 64*32
  ushort* Bs = smem + 2048;              // 128*32
  const int bx = blockIdx.x;
  const int n0 = bx * 128;
  const int m0 = blockIdx.y * 64;
  const int t = threadIdx.x;
  const int w = t >> 6, lane = t & 63;
  const int quad = lane >> 4, nn = lane & 15;
  const int wm = (w & 1) * 32, wn = (w >> 1) * 64;

  f32x4 acc[2][4];
#pragma unroll
  for (int i = 0; i < 2; i++)
#pragma unroll
    for (int j = 0; j < 4; j++) acc[i][j] = (f32x4){0.f, 0.f, 0.f, 0.f};

  for (int k0 = 0; k0 < HID; k0 += 32) {
    __syncthreads();
#pragma unroll
    for (int c = 0; c < 3; c++) {
      int ch = w * 3 + c;
      int rr = (lane >> 2), cl = lane & 3;
      if (ch < 4) {
        int r = ch * 16 + rr;
        int cg = cl ^ ((r >> 1) & 3);
        gload16(A + (size_t)(m0 + r) * HID + k0 + cg * 8, &As[r * 32 + cl * 8]);
      } else {
        int r = (ch - 4) * 16 + rr;
        int cg = cl ^ ((r >> 1) & 3);
        gload16(Bt + (size_t)(n0 + r) * HID + k0 + cg * 8, &Bs[r * 32 + cl * 8]);
      }
    }
    __syncthreads();

    bf16x8 aF[2], bF[4];
#pragma unroll
    for (int i = 0; i < 2; i++) {
      int ra = wm + i * 16 + nn;
      aF[i] = *(const bf16x8*)(&As[ra * 32 + (quad ^ ((ra >> 1) & 3)) * 8]);
    }
#pragma unroll
    for (int j = 0; j < 4; j++) {
      int rb = wn + j * 16 + nn;
      bF[j] = *(const bf16x8*)(&Bs[rb * 32 + (quad ^ ((rb >> 1) & 3)) * 8]);
    }
#pragma unroll
    for (int i = 0; i < 2; i++)
#pragma unroll
      for (int j = 0; j < 4; j++)
        acc[i][j] = __builtin_amdgcn_mfma_f32_16x16x32_bf16(aF[i], bF[j], acc[i][j], 0, 0, 0);
  }

  float bv[4];
#pragma unroll
  for (int j = 0; j < 4; j++) bv[j] = biasQ[n0 + wn + j * 16 + nn];

  if (bx < 8) {
    // RoPE -> LDS transpose (2 heads x 64 rows x 66) -> coalesced stores
    __syncthreads();                      // staging reads of last k-iter done
    const int ht = w >> 1;
    ushort* T = smem + ht * 4224;
#pragma unroll
    for (int i = 0; i < 2; i++) {
#pragma unroll
      for (int r = 0; r < 4; r++) {
        int row = wm + i * 16 + quad * 4 + r;
        int m = m0 + row;
        float2 cs0 = tab[m * 32 + nn];
        float2 cs1 = tab[m * 32 + 16 + nn];
        float x0 = acc[i][0][r] + bv[0];
        float x1 = acc[i][1][r] + bv[1];
        float x2 = acc[i][2][r] + bv[2];
        float x3 = acc[i][3][r] + bv[3];
        T[row * 66 + nn]      = f2bs(x0 * cs0.x - x2 * cs0.y);
        T[row * 66 + 16 + nn] = f2bs(x1 * cs1.x - x3 * cs1.y);
        T[row * 66 + 32 + nn] = f2bs(x2 * cs0.x + x0 * cs0.y);
        T[row * 66 + 48 + nn] = f2bs(x3 * cs1.x + x1 * cs1.y);
      }
    }
    __syncthreads();
    const int ht2 = t >> 7, tl = t & 127, row2 = tl >> 1, col0 = (tl & 1) * 32;
    const int m = m0 + row2, b = m >> 11, n = m & (NN - 1);
    const int hg = bx * 2 + ht2;
    ushort* dst = (hg < HQ)
        ? Qo + ((size_t)(b * HQ + hg) * NN + n) * DD + col0
        : Ko + ((size_t)(b * HKV + (hg - HQ)) * NN + n) * DD + col0;
    const ushort* src = smem + ht2 * 4224 + row2 * 66 + col0;
#pragma unroll
    for (int u = 0; u < 4; u++) ((uint4*)dst)[u] = ((const uint4*)src)[u];
  } else {
    // V: bias + transpose via LDS -> Vt[b][kvh][d][n]
    __syncthreads();
    const int kvh = wn >> 6;
    ushort* T = smem + kvh * (64 * 72);
#pragma unroll
    for (int j = 0; j < 4; j++) {
      int dd = j * 16 + nn;
      float bvj = bv[j];
#pragma unroll
      for (int i = 0; i < 2; i++) {
        int mloc = wm + i * 16 + quad * 4;
        ushort4 pk;
        pk.x = f2bs(acc[i][j][0] + bvj);
        pk.y = f2bs(acc[i][j][1] + bvj);
        pk.z = f2bs(acc[i][j][2] + bvj);
        pk.w = f2bs(acc[i][j][3] + bvj);
        *(ushort4*)(&T[dd * 72 + mloc]) = pk;
      }
    }
    __syncthreads();
    const int head = t >> 7, dd2 = (t >> 1) & 63, seg = t & 1;
    const int b = m0 >> 11, nbase = (m0 & (NN - 1)) + seg * 32;
    const ushort* src = smem + head * (64 * 72) + dd2 * 72 + seg * 32;
    ushort* d = Vto + ((size_t)(b * HKV + head) * DD + dd2) * NN + nbase;
#pragma unroll
    for (int u = 0; u < 4; u++) ((uint4*)d)[u] = ((const uint4*)src)[u];
  }
}

// ---------------------------------------------------------------------------
// o-projection GEMM (64x128, BK=32), fp32 out.
// ---------------------------------------------------------------------------
__global__ __launch_bounds__(256)
void gemm_o(const ushort* __restrict__ A, const ushort* __restrict__ Bt,
            float* __restrict__ out)
{
  const int n0 = blockIdx.x * 128;
  const int m0 = blockIdx.y * 64;
  __shared__ ushort As[64 * 32];
  __shared__ ushort Bs[128 * 32];
  const int t = threadIdx.x;
  const int w = t >> 6, lane = t & 63;
  const int quad = lane >> 4, nn = lane & 15;
  const int wm = (w & 1) * 32, wn = (w >> 1) * 64;

  f32x4 acc[2][4];
#pragma unroll
  for (int i = 0; i < 2; i++)
#pragma unroll
    for (int j = 0; j < 4; j++) acc[i][j] = (f32x4){0.f, 0.f, 0.f, 0.f};

  for (int k0 = 0; k0 < HID; k0 += 32) {
    __syncthreads();
#pragma unroll
    for (int c = 0; c < 3; c++) {
      int ch = w * 3 + c;
      int rr = (lane >> 2), cl = lane & 3;
      if (ch < 4) {
        int r = ch * 16 + rr;
        int cg = cl ^ ((r >> 1) & 3);
        gload16(A + (size_t)(m0 + r) * HID + k0 + cg * 8, &As[r * 32 + cl * 8]);
      } else {
        int r = (ch - 4) * 16 + rr;
        int cg = cl ^ ((r >> 1) & 3);
        gload16(Bt + (size_t)(n0 + r) * HID + k0 + cg * 8, &Bs[r * 32 + cl * 8]);
      }
    }
    __syncthreads();

    bf16x8 aF[2], bF[4];
#pragma unroll
    for (int i = 0; i < 2; i++) {
      int ra = wm + i * 16 + nn;
      aF[i] = *(const bf16x8*)(&As[ra * 32 + (quad ^ ((ra >> 1) & 3)) * 8]);
    }
#pragma unroll
    for (int j = 0; j < 4; j++) {
      int rb = wn + j * 16 + nn;
      bF[j] = *(const bf16x8*)(&Bs[rb * 32 + (quad ^ ((rb >> 1) & 3)) * 8]);
    }
#pragma unroll
    for (int i = 0; i < 2; i++)
#pragma unroll
      for (int j = 0; j < 4; j++)
        acc[i][j] = __builtin_amdgcn_mfma_f32_16x16x32_bf16(aF[i], bF[j], acc[i][j], 0, 0, 0);
  }

#pragma unroll
  for (int j = 0; j < 4; j++) {
    const int col = n0 + wn + j * 16 + nn;
#pragma unroll
    for (int i = 0; i < 2; i++) {
      const int row = m0 + wm + i * 16 + quad * 4;
#pragma unroll
      for (int r = 0; r < 4; r++)
        out[(size_t)(row + r) * HID + col] = acc[i][j][r];
    }
  }
}

// ---------------------------------------------------------------------------
// Barrier-free flash attention: ONE WAVE PER BLOCK (64 thr), 32 Q-rows/wave.
// K/V fragments read directly from global (L2-resident, no redundancy at
// 32-row granularity). P round-trips through wave-private LDS (stride 66,
// <=2-way banks) with wave-internal lgkm ordering only — NO __syncthreads.
// grid (96, HQ, BB): u<32 -> qt=u full-causal (1..16 iters, direct write);
// u>=32 -> qt=32+(v>>1), two 1024-key chunks -> bf16 partials + reduce.
// Softmax in raw-S units, scale 1/8 folded into exp; DPP 16-lane reductions.
// ---------------------------------------------------------------------------
__global__ __launch_bounds__(64)
void attn_kernel(const ushort* __restrict__ Q, const ushort* __restrict__ K,
                 const ushort* __restrict__ Vt, ushort* __restrict__ O,
                 ushort* __restrict__ Opart, float* __restrict__ mpart,
                 float* __restrict__ lpart)
{
  const int u = 95 - (int)blockIdx.x;       // heavy blocks first
  int qt, c;
  if (u < 32) { qt = u; c = 0; }
  else        { int v = u - 32; qt = 32 + (v >> 1); c = v & 1; }
  const int h = blockIdx.y, b = blockIdx.z;
  const int kvh = h / (HQ / HKV);
  const int q0 = qt * 32;
  const int jdiag = qt >> 1;
  const int nc = (qt < 32) ? 1 : 2;
  const int jlo = c * 16;
  const int jhi = (jdiag < jlo + 15) ? jdiag : (jlo + 15);

  __shared__ ushort Ps[32 * 66];            // wave-private P (rows 32)

  const int lane = threadIdx.x;
  const int quad = lane >> 4, nn = lane & 15;

  const ushort* Qb = Q + ((size_t)(b * HQ + h) * NN + q0) * DD;
  bf16x8 aQ[2][2];
#pragma unroll
  for (int mt = 0; mt < 2; mt++)
#pragma unroll
    for (int ks = 0; ks < 2; ks++)
      aQ[mt][ks] = *(const bf16x8*)(Qb + (size_t)(mt * 16 + nn) * DD + ks * 32 + quad * 8);

  const ushort* Kb  = K  + (size_t)(b * HKV + kvh) * NN * DD;
  const ushort* Vtb = Vt + (size_t)(b * HKV + kvh) * DD * NN;

  f32x4 acc[2][4];
#pragma unroll
  for (int mt = 0; mt < 2; mt++)
#pragma unroll
    for (int dt = 0; dt < 4; dt++) acc[mt][dt] = (f32x4){0.f, 0.f, 0.f, 0.f};
  float mst[2][4], lac[2][4];
#pragma unroll
  for (int mt = 0; mt < 2; mt++)
#pragma unroll
    for (int r = 0; r < 4; r++) { mst[mt][r] = -1e30f; lac[mt][r] = 0.f; }

  for (int j = jlo; j <= jhi; j++) {
    const bool diag = (j == jdiag);
    const int ctmax = diag ? ((qt & 1) ? 3 : 1) : 3;
    const int ksmax = (ctmax == 1) ? 0 : 1;

    // S = Q K^T (K frags direct from global/L2)
    f32x4 sf[2][4];
#pragma unroll
    for (int ct = 0; ct < 4; ct++) {
      if (ct <= ctmax) {
        const ushort* kr = Kb + (size_t)(j * 64 + ct * 16 + nn) * DD;
        bf16x8 bk0 = *(const bf16x8*)(kr + quad * 8);
        bf16x8 bk1 = *(const bf16x8*)(kr + 32 + quad * 8);
#pragma unroll
        for (int mt = 0; mt < 2; mt++) {
          f32x4 cc = __builtin_amdgcn_mfma_f32_16x16x32_bf16(aQ[mt][0], bk0,
                         (f32x4){0.f, 0.f, 0.f, 0.f}, 0, 0, 0);
          sf[mt][ct] = __builtin_amdgcn_mfma_f32_16x16x32_bf16(aQ[mt][1], bk1, cc, 0, 0, 0);
        }
      }
    }

    // V fragments issued early (latency hidden under softmax)
    bf16x8 bvf[2][4];
#pragma unroll
    for (int ks = 0; ks < 2; ks++)
      if (ks <= ksmax)
#pragma unroll
        for (int dt = 0; dt < 4; dt++)
          bvf[ks][dt] = *(const bf16x8*)(Vtb + (size_t)(dt * 16 + nn) * NN +
                                         j * 64 + ks * 32 + quad * 8);

    // mask + online softmax (per-lane rows: mt*16 + quad*4 + r)
    float s[2][4][4];
#pragma unroll
    for (int ct = 0; ct < 4; ct++)
#pragma unroll
      for (int mt = 0; mt < 2; mt++)
#pragma unroll
        for (int r = 0; r < 4; r++) {
          float v = -1e30f;
          if (ct <= ctmax) {
            v = sf[mt][ct][r];
            if (diag && (j * 64 + ct * 16 + nn) > (q0 + mt * 16 + quad * 4 + r))
              v = -1e30f;
          }
          s[mt][ct][r] = v;
        }
#pragma unroll
    for (int mt = 0; mt < 2; mt++)
#pragma unroll
      for (int r = 0; r < 4; r++) {
        float mt_ = fmaxf(fmaxf(s[mt][0][r], s[mt][1][r]), fmaxf(s[mt][2][r], s[mt][3][r]));
        mt_ = dpp_fmax16(mt_);
        float mn = fmaxf(mst[mt][r], mt_);
        float alpha = __expf((mst[mt][r] - mn) * 0.125f);
        mst[mt][r] = mn;
        float lloc = 0.f;
#pragma unroll
        for (int ct = 0; ct < 4; ct++) {
          float p = __expf((s[mt][ct][r] - mn) * 0.125f);
          s[mt][ct][r] = p;
          lloc += p;
        }
        lac[mt][r] = lac[mt][r] * alpha + lloc;
#pragma unroll
        for (int dt = 0; dt < 4; dt++) acc[mt][dt][r] *= alpha;
      }

    // P -> wave-private LDS (C-layout) -> A-layout frags (lgkm only, no barrier)
#pragma unroll
    for (int mt = 0; mt < 2; mt++)
#pragma unroll
      for (int ct = 0; ct < 4; ct++)
#pragma unroll
        for (int r = 0; r < 4; r++)
          Ps[(mt * 16 + quad * 4 + r) * 66 + ct * 16 + nn] = f2bs(s[mt][ct][r]);

#pragma unroll
    for (int mt = 0; mt < 2; mt++) {
#pragma unroll
      for (int ks = 0; ks < 2; ks++) {
        if (ks <= ksmax) {
          bf16x8 aP = *(const bf16x8*)(&Ps[(mt * 16 + nn) * 66 + ks * 32 + quad * 8]);
#pragma unroll
          for (int dt = 0; dt < 4; dt++)
            acc[mt][dt] = __builtin_amdgcn_mfma_f32_16x16x32_bf16(aP, bvf[ks][dt],
                                                                  acc[mt][dt], 0, 0, 0);
        }
      }
    }
  }

  float ltot[2][4];
#pragma unroll
  for (int mt = 0; mt < 2; mt++)
#pragma unroll
    for (int r = 0; r < 4; r++) ltot[mt][r] = dpp_fadd16(lac[mt][r]);

  if (nc == 1) {
#pragma unroll
    for (int mt = 0; mt < 2; mt++)
#pragma unroll
      for (int r = 0; r < 4; r++) {
        float linv = 1.f / (ltot[mt][r] + 1e-8f);
#pragma unroll
        for (int dt = 0; dt < 4; dt++)
          O[(size_t)(b * NN + q0 + mt * 16 + quad * 4 + r) * HID + h * DD + dt * 16 + nn] =
              f2bs(acc[mt][dt][r] * linv);
      }
  } else {
    const int p = (b * HQ + h) * 64 + (qt - 32) * 2 + c;
    ushort* Op = Opart + (size_t)p * 2048;
#pragma unroll
    for (int mt = 0; mt < 2; mt++)
#pragma unroll
      for (int r = 0; r < 4; r++) {
#pragma unroll
        for (int dt = 0; dt < 4; dt++)
          Op[(mt * 16 + quad * 4 + r) * 64 + dt * 16 + nn] = f2bs(acc[mt][dt][r]);
        if (nn == 0) {
          mpart[(size_t)p * 32 + mt * 16 + quad * 4 + r] = mst[mt][r];   // raw S units
          lpart[(size_t)p * 32 + mt * 16 + quad * 4 + r] = ltot[mt][r];
        }
      }
  }
}

// ---------------------------------------------------------------------------
// Reduce: merge the 2 chunk-partials for qt 32..63. grid (32, 14, 2), 256 thr.
// thread = (row = t>>3, 8-col seg = t&7); fully coalesced uint4 IO.
// ---------------------------------------------------------------------------
__global__ __launch_bounds__(256)
void attn_reduce_kernel(const ushort* __restrict__ Opart, const float* __restrict__ mpart,
                        const float* __restrict__ lpart, ushort* __restrict__ O)
{
  const int qt = 32 + blockIdx.x;
  const int h = blockIdx.y, b = blockIdx.z;
  const int p0 = (b * HQ + h) * 64 + (qt - 32) * 2;
  const int t = threadIdx.x;
  const int row = t >> 3, seg = t & 7;

  float m0v = mpart[(size_t)p0 * 32 + row];
  float m1v = mpart[(size_t)(p0 + 1) * 32 + row];
  float l0 = lpart[(size_t)p0 * 32 + row];
  float l1 = lpart[(size_t)(p0 + 1) * 32 + row];
  float M = fmaxf(m0v, m1v);
  float w0 = __expf((m0v - M) * 0.125f);
  float w1 = __expf((m1v - M) * 0.125f);
  const float linv = 1.f / (l0 * w0 + l1 * w1 + 1e-8f);

  const ushort* Op0 = Opart + (size_t)p0 * 2048 + row * 64 + seg * 8;
  const ushort* Op1 = Op0 + 2048;
  ushort ov[8];
#pragma unroll
  for (int k = 0; k < 8; k++)
    ov[k] = f2bs((w0 * bs2f(Op0[k]) + w1 * bs2f(Op1[k])) * linv);
  ushort* Od = O + (size_t)(b * NN + qt * 32 + row) * HID + h * DD + seg * 8;
  *(uint4*)Od = *(uint4*)ov;
}

// ---------------------------------------------------------------------------
extern "C" void kernel_launch(void* const* d_in, const int* in_sizes, int n_in,
                              void* d_out, int out_size, void* d_ws, size_t ws_size,
                              hipStream_t stream)
{
  const float* hid = (const float*)d_in[0];
  const int*   pos = (const int*)  d_in[1];
  const float* qw  = (const float*)d_in[2];
  const float* qb  = (const float*)d_in[3];
  const float* kw  = (const float*)d_in[4];
  const float* kb  = (const float*)d_in[5];
  const float* vw  = (const float*)d_in[6];
  const float* vb  = (const float*)d_in[7];
  const float* ow  = (const float*)d_in[8];
  float* outp = (float*)d_out;

  // ws (ushort units). Opart (28*64 slots x 2048 = 3,670,016) overlays Ah.
  ushort* WqkvT = (ushort*)d_ws;                          // 1,032,192
  ushort* WoT   = WqkvT + (size_t)QKV_COLS * HID;         //   802,816
  ushort* Ah    = WoT   + (size_t)HID * HID;              // 3,670,016
  ushort* Qb    = Ah    + (size_t)4096 * HID;             // 3,670,016
  ushort* Kb    = Qb    + (size_t)BB * HQ  * NN * DD;     //   524,288
  ushort* Vtb   = Kb    + (size_t)BB * HKV * NN * DD;     //   524,288
  ushort* Ob    = Vtb   + (size_t)BB * HKV * NN * DD;     // 3,670,016
  float2* tab   = (float2*)(Ob + (size_t)4096 * HID);     // 4096*32 float2
  float*  biasQ = (float*)(tab + (size_t)4096 * 32);      // 1152
  float*  mpart = biasQ + QKV_COLS;                       // 28*64*32 = 57,344
  float*  lpart = mpart + (size_t)28 * 64 * 32;
  ushort* Opart = Ah;                                     // overlay (dead region)

  prep_kernel<<<dim3(5893), 256, 0, stream>>>(hid, pos, qw, kw, vw, ow, qb, kb, vb,
                                              Ah, WqkvT, WoT, tab, biasQ);
  gemm_qkv_rope<<<dim3(9, 64), 256, 0, stream>>>(Ah, WqkvT, biasQ, tab, Qb, Kb, Vtb);
  attn_kernel<<<dim3(96, HQ, BB), 64, 0, stream>>>(Qb, Kb, Vtb, Ob, Opart, mpart, lpart);
  attn_reduce_kernel<<<dim3(32, HQ, BB), 256, 0, stream>>>(Opart, mpart, lpart, Ob);
  gemm_o<<<dim3(HID / 128, 64), 256, 0, stream>>>(Ob, WoT, outp);
}

// Round 7
// 218.208 us; speedup vs baseline: 1.2262x; 1.1192x over previous
//
#include <hip/hip_runtime.h>
#include <math.h>

#define BB 2
#define NN 2048
#define HID 896
#define HQ 14
#define HKV 2
#define DD 64
#define QKV_COLS 1152
#define QSCALE 0.18033688011112042f   // 0.125 * log2(e), folded into Q

typedef __bf16 bf16x8 __attribute__((ext_vector_type(8)));
typedef float f32x4 __attribute__((ext_vector_type(4)));

__device__ inline ushort f2bs(float f) {   // fp32 -> bf16 (RNE), finite inputs
  uint u = __builtin_bit_cast(uint, f);
  u += 0x7FFFu + ((u >> 16) & 1u);
  return (ushort)(u >> 16);
}
__device__ inline float bs2f(ushort u) {
  return __builtin_bit_cast(float, (uint)u << 16);
}

__device__ inline void gload16(const ushort* g, ushort* l) {
  __builtin_amdgcn_global_load_lds(
      (const __attribute__((address_space(1))) uint*)g,
      (__attribute__((address_space(3))) uint*)l, 16, 0, 0);
}

// 16-lane reductions on the VALU pipe (DPP): quad_perm xor1, xor2, row_ror 4/8
__device__ inline float dpp_fmax16(float x) {
  int v;
  v = __builtin_amdgcn_update_dpp(0, __builtin_bit_cast(int, x), 0xB1, 0xF, 0xF, true);
  x = fmaxf(x, __builtin_bit_cast(float, v));
  v = __builtin_amdgcn_update_dpp(0, __builtin_bit_cast(int, x), 0x4E, 0xF, 0xF, true);
  x = fmaxf(x, __builtin_bit_cast(float, v));
  v = __builtin_amdgcn_update_dpp(0, __builtin_bit_cast(int, x), 0x124, 0xF, 0xF, true);
  x = fmaxf(x, __builtin_bit_cast(float, v));
  v = __builtin_amdgcn_update_dpp(0, __builtin_bit_cast(int, x), 0x128, 0xF, 0xF, true);
  x = fmaxf(x, __builtin_bit_cast(float, v));
  return x;
}
__device__ inline float dpp_fadd16(float x) {
  int v;
  v = __builtin_amdgcn_update_dpp(0, __builtin_bit_cast(int, x), 0xB1, 0xF, 0xF, true);
  x += __builtin_bit_cast(float, v);
  v = __builtin_amdgcn_update_dpp(0, __builtin_bit_cast(int, x), 0x4E, 0xF, 0xF, true);
  x += __builtin_bit_cast(float, v);
  v = __builtin_amdgcn_update_dpp(0, __builtin_bit_cast(int, x), 0x124, 0xF, 0xF, true);
  x += __builtin_bit_cast(float, v);
  v = __builtin_amdgcn_update_dpp(0, __builtin_bit_cast(int, x), 0x128, 0xF, 0xF, true);
  x += __builtin_bit_cast(float, v);
  return x;
}

// ---------------------------------------------------------------------------
// prep: [0,3584) cast hidden->bf16 | [3584,4592) qkv-w pack | [4592,5376) o-w
// pack | [5376,5888) rope cos/sin table | [5888,5893) bias pack
// ---------------------------------------------------------------------------
__global__ __launch_bounds__(256)
void prep_kernel(const float* __restrict__ hid, const int* __restrict__ pos,
                 const float* __restrict__ qw, const float* __restrict__ kw,
                 const float* __restrict__ vw, const float* __restrict__ ow,
                 const float* __restrict__ qb, const float* __restrict__ kb,
                 const float* __restrict__ vb,
                 ushort* __restrict__ Ah, ushort* __restrict__ WqkvT,
                 ushort* __restrict__ WoT, float2* __restrict__ tab,
                 float* __restrict__ biasQ)
{
  __shared__ float tile[32][33];
  const int blk = blockIdx.x, t = threadIdx.x;
  if (blk < 3584) {
    int i = blk * 256 + t;
    float4 v = ((const float4*)hid)[i];
    ushort4 o;
    o.x = f2bs(v.x); o.y = f2bs(v.y); o.z = f2bs(v.z); o.w = f2bs(v.w);
    ((ushort4*)Ah)[i] = o;
  } else if (blk < 5376) {
    const float* src; int N, n0, drow, k0;
    if (blk < 4592) {
      int idx = blk - 3584;
      int bx = idx % 36; k0 = (idx / 36) * 32;
      if (bx < 28)      { src = qw; N = 896; n0 = bx * 32;        drow = n0; }
      else if (bx < 32) { src = kw; N = 128; n0 = (bx - 28) * 32; drow = 896 + n0; }
      else              { src = vw; N = 128; n0 = (bx - 32) * 32; drow = 1024 + n0; }
    } else {
      int idx = blk - 4592;
      src = ow; N = 896; n0 = (idx % 28) * 32; k0 = (idx / 28) * 32; drow = n0;
    }
    ushort* dst = (blk < 4592) ? WqkvT : WoT;
    const int tx = t & 31, ty = t >> 5;
#pragma unroll
    for (int i = 0; i < 32; i += 8)
      tile[ty + i][tx] = src[(size_t)(k0 + ty + i) * N + n0 + tx];
    __syncthreads();
#pragma unroll
    for (int i = 0; i < 32; i += 8)
      dst[(size_t)(drow + ty + i) * HID + k0 + tx] = f2bs(tile[tx][ty + i]);
  } else if (blk < 5888) {
    int idx = (blk - 5376) * 256 + t;     // 0 .. 131071
    int m = idx >> 5, f = idx & 31;
    float inv = exp2f(-(float)f * (19.9315685693241741f / 32.0f));
    float ang = (float)pos[m] * inv;
    float sv, cv;
    sincosf(ang, &sv, &cv);
    tab[idx] = make_float2(cv, sv);
  } else {
    int i = (blk - 5888) * 256 + t;
    if (i < QKV_COLS)
      biasQ[i] = (i < 896) ? qb[i] : (i < 1024 ? kb[i - 896] : vb[i - 1024]);
  }
}

// ---------------------------------------------------------------------------
// QKV GEMM (64x128 tile, BK=32) with fused bias + RoPE + scatter epilogue.
// grid (9, 64). bx<8: Q/K cols -> (Q pre-scaled by QSCALE) rope -> LDS
// transpose -> coalesced stores. bx==8: V cols -> LDS transpose -> Vt.
// ---------------------------------------------------------------------------
__global__ __launch_bounds__(256)
void gemm_qkv_rope(const ushort* __restrict__ A, const ushort* __restrict__ Bt,
                   const float* __restrict__ biasQ, const float2* __restrict__ tab,
                   ushort* __restrict__ Qo, ushort* __restrict__ Ko,
                   ushort* __restrict__ Vto)
{
  __shared__ ushort smem[9216];          // staging 6144 | QK-T 8448 | V-T 9216
  ushort* As = smem;                     // 64*32
  ushort* Bs = smem + 2048;              // 128*32
  const int bx = blockIdx.x;
  const int n0 = bx * 128;
  const int m0 = blockIdx.y * 64;
  const int t = threadIdx.x;
  const int w = t >> 6, lane = t & 63;
  const int quad = lane >> 4, nn = lane & 15;
  const int wm = (w & 1) * 32, wn = (w >> 1) * 64;

  f32x4 acc[2][4];
#pragma unroll
  for (int i = 0; i < 2; i++)
#pragma unroll
    for (int j = 0; j < 4; j++) acc[i][j] = (f32x4){0.f, 0.f, 0.f, 0.f};

  for (int k0 = 0; k0 < HID; k0 += 32) {
    __syncthreads();
#pragma unroll
    for (int c = 0; c < 3; c++) {
      int ch = w * 3 + c;
      int rr = (lane >> 2), cl = lane & 3;
      if (ch < 4) {
        int r = ch * 16 + rr;
        int cg = cl ^ ((r >> 1) & 3);
        gload16(A + (size_t)(m0 + r) * HID + k0 + cg * 8, &As[r * 32 + cl * 8]);
      } else {
        int r = (ch - 4) * 16 + rr;
        int cg = cl ^ ((r >> 1) & 3);
        gload16(Bt + (size_t)(n0 + r) * HID + k0 + cg * 8, &Bs[r * 32 + cl * 8]);
      }
    }
    __syncthreads();

    bf16x8 aF[2], bF[4];
#pragma unroll
    for (int i = 0; i < 2; i++) {
      int ra = wm + i * 16 + nn;
      aF[i] = *(const bf16x8*)(&As[ra * 32 + (quad ^ ((ra >> 1) & 3)) * 8]);
    }
#pragma unroll
    for (int j = 0; j < 4; j++) {
      int rb = wn + j * 16 + nn;
      bF[j] = *(const bf16x8*)(&Bs[rb * 32 + (quad ^ ((rb >> 1) & 3)) * 8]);
    }
#pragma unroll
    for (int i = 0; i < 2; i++)
#pragma unroll
      for (int j = 0; j < 4; j++)
        acc[i][j] = __builtin_amdgcn_mfma_f32_16x16x32_bf16(aF[i], bF[j], acc[i][j], 0, 0, 0);
  }

  float bv[4];
#pragma unroll
  for (int j = 0; j < 4; j++) bv[j] = biasQ[n0 + wn + j * 16 + nn];

  if (bx < 8) {
    // Q heads get QSCALE (bx<7 => both heads Q; bx==7 => both K). Wave-uniform.
    const float qs = (bx < 7) ? QSCALE : 1.0f;
    __syncthreads();                      // staging reads of last k-iter done
    const int ht = w >> 1;
    ushort* T = smem + ht * 4224;
#pragma unroll
    for (int i = 0; i < 2; i++) {
#pragma unroll
      for (int r = 0; r < 4; r++) {
        int row = wm + i * 16 + quad * 4 + r;
        int m = m0 + row;
        float2 cs0 = tab[m * 32 + nn];
        float2 cs1 = tab[m * 32 + 16 + nn];
        float x0 = (acc[i][0][r] + bv[0]) * qs;
        float x1 = (acc[i][1][r] + bv[1]) * qs;
        float x2 = (acc[i][2][r] + bv[2]) * qs;
        float x3 = (acc[i][3][r] + bv[3]) * qs;
        T[row * 66 + nn]      = f2bs(x0 * cs0.x - x2 * cs0.y);
        T[row * 66 + 16 + nn] = f2bs(x1 * cs1.x - x3 * cs1.y);
        T[row * 66 + 32 + nn] = f2bs(x2 * cs0.x + x0 * cs0.y);
        T[row * 66 + 48 + nn] = f2bs(x3 * cs1.x + x1 * cs1.y);
      }
    }
    __syncthreads();
    const int ht2 = t >> 7, tl = t & 127, row2 = tl >> 1, col0 = (tl & 1) * 32;
    const int m = m0 + row2, b = m >> 11, n = m & (NN - 1);
    const int hg = bx * 2 + ht2;
    ushort* dst = (hg < HQ)
        ? Qo + ((size_t)(b * HQ + hg) * NN + n) * DD + col0
        : Ko + ((size_t)(b * HKV + (hg - HQ)) * NN + n) * DD + col0;
    const ushort* src = smem + ht2 * 4224 + row2 * 66 + col0;
#pragma unroll
    for (int u = 0; u < 4; u++) ((uint4*)dst)[u] = ((const uint4*)src)[u];
  } else {
    // V: bias + transpose via LDS -> Vt[b][kvh][d][n]
    __syncthreads();
    const int kvh = wn >> 6;
    ushort* T = smem + kvh * (64 * 72);
#pragma unroll
    for (int j = 0; j < 4; j++) {
      int dd = j * 16 + nn;
      float bvj = bv[j];
#pragma unroll
      for (int i = 0; i < 2; i++) {
        int mloc = wm + i * 16 + quad * 4;
        ushort4 pk;
        pk.x = f2bs(acc[i][j][0] + bvj);
        pk.y = f2bs(acc[i][j][1] + bvj);
        pk.z = f2bs(acc[i][j][2] + bvj);
        pk.w = f2bs(acc[i][j][3] + bvj);
        *(ushort4*)(&T[dd * 72 + mloc]) = pk;
      }
    }
    __syncthreads();
    const int head = t >> 7, dd2 = (t >> 1) & 63, seg = t & 1;
    const int b = m0 >> 11, nbase = (m0 & (NN - 1)) + seg * 32;
    const ushort* src = smem + head * (64 * 72) + dd2 * 72 + seg * 32;
    ushort* d = Vto + ((size_t)(b * HKV + head) * DD + dd2) * NN + nbase;
#pragma unroll
    for (int u = 0; u < 4; u++) ((uint4*)d)[u] = ((const uint4*)src)[u];
  }
}

// ---------------------------------------------------------------------------
// o-projection GEMM (64x128, BK=32), fp32 out.
// ---------------------------------------------------------------------------
__global__ __launch_bounds__(256)
void gemm_o(const ushort* __restrict__ A, const ushort* __restrict__ Bt,
            float* __restrict__ out)
{
  const int n0 = blockIdx.x * 128;
  const int m0 = blockIdx.y * 64;
  __shared__ ushort As[64 * 32];
  __shared__ ushort Bs[128 * 32];
  const int t = threadIdx.x;
  const int w = t >> 6, lane = t & 63;
  const int quad = lane >> 4, nn = lane & 15;
  const int wm = (w & 1) * 32, wn = (w >> 1) * 64;

  f32x4 acc[2][4];
#pragma unroll
  for (int i = 0; i < 2; i++)
#pragma unroll
    for (int j = 0; j < 4; j++) acc[i][j] = (f32x4){0.f, 0.f, 0.f, 0.f};

  for (int k0 = 0; k0 < HID; k0 += 32) {
    __syncthreads();
#pragma unroll
    for (int c = 0; c < 3; c++) {
      int ch = w * 3 + c;
      int rr = (lane >> 2), cl = lane & 3;
      if (ch < 4) {
        int r = ch * 16 + rr;
        int cg = cl ^ ((r >> 1) & 3);
        gload16(A + (size_t)(m0 + r) * HID + k0 + cg * 8, &As[r * 32 + cl * 8]);
      } else {
        int r = (ch - 4) * 16 + rr;
        int cg = cl ^ ((r >> 1) & 3);
        gload16(Bt + (size_t)(n0 + r) * HID + k0 + cg * 8, &Bs[r * 32 + cl * 8]);
      }
    }
    __syncthreads();

    bf16x8 aF[2], bF[4];
#pragma unroll
    for (int i = 0; i < 2; i++) {
      int ra = wm + i * 16 + nn;
      aF[i] = *(const bf16x8*)(&As[ra * 32 + (quad ^ ((ra >> 1) & 3)) * 8]);
    }
#pragma unroll
    for (int j = 0; j < 4; j++) {
      int rb = wn + j * 16 + nn;
      bF[j] = *(const bf16x8*)(&Bs[rb * 32 + (quad ^ ((rb >> 1) & 3)) * 8]);
    }
#pragma unroll
    for (int i = 0; i < 2; i++)
#pragma unroll
      for (int j = 0; j < 4; j++)
        acc[i][j] = __builtin_amdgcn_mfma_f32_16x16x32_bf16(aF[i], bF[j], acc[i][j], 0, 0, 0);
  }

#pragma unroll
  for (int j = 0; j < 4; j++) {
    const int col = n0 + wn + j * 16 + nn;
#pragma unroll
    for (int i = 0; i < 2; i++) {
      const int row = m0 + wm + i * 16 + quad * 4;
#pragma unroll
      for (int r = 0; r < 4; r++)
        out[(size_t)(row + r) * HID + col] = acc[i][j][r];
    }
  }
}

// ---------------------------------------------------------------------------
// Flash attention step: branch-free bulk (DIAG=false) or masked diagonal tile
// (DIAG=true). All 16 K/V b128 loads are unconditional -> batched in flight.
// Q is pre-scaled by 0.125*log2(e) so softmax uses bare exp2f.
// ---------------------------------------------------------------------------
template <bool DIAG>
__device__ __forceinline__ void attn_step(
    int j, int qt, int quad, int nn,
    const ushort* __restrict__ Kb, const ushort* __restrict__ Vtb,
    ushort* __restrict__ Ps, const bf16x8 (&aQ)[2][2],
    f32x4 (&acc)[2][4], float (&mst)[2][4], float (&lac)[2][4])
{
  bf16x8 bk0[4], bk1[4];
#pragma unroll
  for (int ct = 0; ct < 4; ct++) {
    const ushort* kr = Kb + (size_t)(j * 64 + ct * 16 + nn) * DD;
    bk0[ct] = *(const bf16x8*)(kr + quad * 8);
    bk1[ct] = *(const bf16x8*)(kr + 32 + quad * 8);
  }
  bf16x8 bv0[4], bv1[4];
#pragma unroll
  for (int dt = 0; dt < 4; dt++) {
    const ushort* vr = Vtb + (size_t)(dt * 16 + nn) * NN + j * 64;
    bv0[dt] = *(const bf16x8*)(vr + quad * 8);
    bv1[dt] = *(const bf16x8*)(vr + 32 + quad * 8);
  }

  f32x4 s[2][4];
#pragma unroll
  for (int ct = 0; ct < 4; ct++)
#pragma unroll
    for (int mt = 0; mt < 2; mt++) {
      f32x4 cc = __builtin_amdgcn_mfma_f32_16x16x32_bf16(
          aQ[mt][0], bk0[ct], (f32x4){0.f, 0.f, 0.f, 0.f}, 0, 0, 0);
      s[mt][ct] = __builtin_amdgcn_mfma_f32_16x16x32_bf16(aQ[mt][1], bk1[ct], cc, 0, 0, 0);
    }

  if (DIAG) {
    const int keyb = j * 64 + nn;
    const int qb_ = qt * 32 + quad * 4;
#pragma unroll
    for (int mt = 0; mt < 2; mt++)
#pragma unroll
      for (int ct = 0; ct < 4; ct++)
#pragma unroll
        for (int r = 0; r < 4; r++)
          if (keyb + ct * 16 > qb_ + mt * 16 + r) s[mt][ct][r] = -1e30f;
  }

#pragma unroll
  for (int mt = 0; mt < 2; mt++)
#pragma unroll
    for (int r = 0; r < 4; r++) {
      float mx = fmaxf(fmaxf(s[mt][0][r], s[mt][1][r]), fmaxf(s[mt][2][r], s[mt][3][r]));
      mx = dpp_fmax16(mx);
      float mn = fmaxf(mst[mt][r], mx);
      float alpha = exp2f(mst[mt][r] - mn);
      mst[mt][r] = mn;
      float ll = 0.f;
#pragma unroll
      for (int ct = 0; ct < 4; ct++) {
        float p = exp2f(s[mt][ct][r] - mn);
        s[mt][ct][r] = p;
        ll += p;
      }
      lac[mt][r] = lac[mt][r] * alpha + ll;
#pragma unroll
      for (int dt = 0; dt < 4; dt++) acc[mt][dt][r] *= alpha;
    }

  // P (C-layout) -> wave-private LDS -> A-layout frags (wave-internal lgkm only)
#pragma unroll
  for (int mt = 0; mt < 2; mt++)
#pragma unroll
    for (int ct = 0; ct < 4; ct++)
#pragma unroll
      for (int r = 0; r < 4; r++)
        Ps[(mt * 16 + quad * 4 + r) * 66 + ct * 16 + nn] = f2bs(s[mt][ct][r]);

#pragma unroll
  for (int mt = 0; mt < 2; mt++) {
    bf16x8 aP0 = *(const bf16x8*)(&Ps[(mt * 16 + nn) * 66 + quad * 8]);
    bf16x8 aP1 = *(const bf16x8*)(&Ps[(mt * 16 + nn) * 66 + 32 + quad * 8]);
#pragma unroll
    for (int dt = 0; dt < 4; dt++) {
      acc[mt][dt] = __builtin_amdgcn_mfma_f32_16x16x32_bf16(aP0, bv0[dt], acc[mt][dt], 0, 0, 0);
      acc[mt][dt] = __builtin_amdgcn_mfma_f32_16x16x32_bf16(aP1, bv1[dt], acc[mt][dt], 0, 0, 0);
    }
  }
}

// ---------------------------------------------------------------------------
// Barrier-free split-KV flash attention: one wave per block, 32 Q-rows.
// Chunks of 14 key-tiles (896 keys). grid.x = 108 per (h,b):
//   u<28: qt=u, nc=1 (direct write); u<84: qt=28+(v>>1), nc=2; else qt=56+v/3, nc=3.
// Bulk iterations are branch-free; the diagonal tile runs once, masked.
// ---------------------------------------------------------------------------
__global__ __launch_bounds__(64, 3)
void attn_kernel(const ushort* __restrict__ Q, const ushort* __restrict__ K,
                 const ushort* __restrict__ Vt, ushort* __restrict__ O,
                 ushort* __restrict__ Opart, float* __restrict__ mpart,
                 float* __restrict__ lpart)
{
  const int u = 107 - (int)blockIdx.x;      // heavy blocks first
  int qt, c;
  if (u < 28)      { qt = u; c = 0; }
  else if (u < 84) { int v = u - 28; qt = 28 + (v >> 1); c = v & 1; }
  else             { int v = u - 84; qt = 56 + v / 3; c = v - (v / 3) * 3; }
  const int h = blockIdx.y, b = blockIdx.z;
  const int kvh = h / (HQ / HKV);
  const int q0 = qt * 32;
  const int jmax = qt >> 1;
  const int nc = jmax / 14 + 1;
  const int jlo = c * 14;
  const int jhi = min(jmax, jlo + 13);
  const bool hasdiag = (jhi == jmax);
  const int jB = hasdiag ? jmax : jhi + 1;  // bulk range [jlo, jB)

  __shared__ ushort Ps[32 * 66];            // wave-private P

  const int lane = threadIdx.x;
  const int quad = lane >> 4, nn = lane & 15;

  const ushort* Qb = Q + ((size_t)(b * HQ + h) * NN + q0) * DD;
  bf16x8 aQ[2][2];
#pragma unroll
  for (int mt = 0; mt < 2; mt++)
#pragma unroll
    for (int ks = 0; ks < 2; ks++)
      aQ[mt][ks] = *(const bf16x8*)(Qb + (size_t)(mt * 16 + nn) * DD + ks * 32 + quad * 8);

  const ushort* Kb  = K  + (size_t)(b * HKV + kvh) * NN * DD;
  const ushort* Vtb = Vt + (size_t)(b * HKV + kvh) * DD * NN;

  f32x4 acc[2][4];
#pragma unroll
  for (int mt = 0; mt < 2; mt++)
#pragma unroll
    for (int dt = 0; dt < 4; dt++) acc[mt][dt] = (f32x4){0.f, 0.f, 0.f, 0.f};
  float mst[2][4], lac[2][4];
#pragma unroll
  for (int mt = 0; mt < 2; mt++)
#pragma unroll
    for (int r = 0; r < 4; r++) { mst[mt][r] = -1e30f; lac[mt][r] = 0.f; }

  for (int j = jlo; j < jB; j++)
    attn_step<false>(j, qt, quad, nn, Kb, Vtb, Ps, aQ, acc, mst, lac);
  if (hasdiag)
    attn_step<true>(jmax, qt, quad, nn, Kb, Vtb, Ps, aQ, acc, mst, lac);

  float ltot[2][4];
#pragma unroll
  for (int mt = 0; mt < 2; mt++)
#pragma unroll
    for (int r = 0; r < 4; r++) ltot[mt][r] = dpp_fadd16(lac[mt][r]);

  if (nc == 1) {
#pragma unroll
    for (int mt = 0; mt < 2; mt++)
#pragma unroll
      for (int r = 0; r < 4; r++) {
        float linv = 1.f / (ltot[mt][r] + 1e-8f);
#pragma unroll
        for (int dt = 0; dt < 4; dt++)
          O[(size_t)(b * NN + q0 + mt * 16 + quad * 4 + r) * HID + h * DD + dt * 16 + nn] =
              f2bs(acc[mt][dt][r] * linv);
      }
  } else {
    const int off = (qt < 56) ? (qt - 28) * 2 : 56 + (qt - 56) * 3;
    const int p = (b * HQ + h) * 80 + off + c;
    ushort* Op = Opart + (size_t)p * 2048;
#pragma unroll
    for (int mt = 0; mt < 2; mt++)
#pragma unroll
      for (int r = 0; r < 4; r++) {
#pragma unroll
        for (int dt = 0; dt < 4; dt++)
          Op[(mt * 16 + quad * 4 + r) * 64 + dt * 16 + nn] = f2bs(acc[mt][dt][r]);
        if (nn == 0) {
          mpart[(size_t)p * 32 + mt * 16 + quad * 4 + r] = mst[mt][r];   // log2 units
          lpart[(size_t)p * 32 + mt * 16 + quad * 4 + r] = ltot[mt][r];
        }
      }
  }
}

// ---------------------------------------------------------------------------
// Reduce: merge 2-3 chunk partials for qt 28..63. grid (36, 14, 2), 256 thr.
// ---------------------------------------------------------------------------
__global__ __launch_bounds__(256)
void attn_reduce_kernel(const ushort* __restrict__ Opart, const float* __restrict__ mpart,
                        const float* __restrict__ lpart, ushort* __restrict__ O)
{
  const int qt = 28 + blockIdx.x;
  const int h = blockIdx.y, b = blockIdx.z;
  const int nc = (qt < 56) ? 2 : 3;
  const int off = (qt < 56) ? (qt - 28) * 2 : 56 + (qt - 56) * 3;
  const int pb = (b * HQ + h) * 80 + off;
  const int t = threadIdx.x;
  const int row = t >> 3, seg = t & 7;

  float mv[3], lv[3];
  float M = -1e30f;
  for (int c = 0; c < nc; c++) {
    mv[c] = mpart[(size_t)(pb + c) * 32 + row];
    lv[c] = lpart[(size_t)(pb + c) * 32 + row];
    M = fmaxf(M, mv[c]);
  }
  float l = 0.f, wv[3];
  for (int c = 0; c < nc; c++) { wv[c] = exp2f(mv[c] - M); l += lv[c] * wv[c]; }
  const float linv = 1.f / (l + 1e-8f);

  float av[8];
#pragma unroll
  for (int k = 0; k < 8; k++) av[k] = 0.f;
  for (int c = 0; c < nc; c++) {
    const ushort* Op = Opart + (size_t)(pb + c) * 2048 + row * 64 + seg * 8;
#pragma unroll
    for (int k = 0; k < 8; k++) av[k] += wv[c] * bs2f(Op[k]);
  }
  ushort ov[8];
#pragma unroll
  for (int k = 0; k < 8; k++) ov[k] = f2bs(av[k] * linv);
  ushort* Od = O + (size_t)(b * NN + qt * 32 + row) * HID + h * DD + seg * 8;
  *(uint4*)Od = *(uint4*)ov;
}

// ---------------------------------------------------------------------------
extern "C" void kernel_launch(void* const* d_in, const int* in_sizes, int n_in,
                              void* d_out, int out_size, void* d_ws, size_t ws_size,
                              hipStream_t stream)
{
  const float* hid = (const float*)d_in[0];
  const int*   pos = (const int*)  d_in[1];
  const float* qw  = (const float*)d_in[2];
  const float* qb  = (const float*)d_in[3];
  const float* kw  = (const float*)d_in[4];
  const float* kb  = (const float*)d_in[5];
  const float* vw  = (const float*)d_in[6];
  const float* vb  = (const float*)d_in[7];
  const float* ow  = (const float*)d_in[8];
  float* outp = (float*)d_out;

  // ws (ushort units). WoT first so WqkvT+Ah form a contiguous dead region for
  // Opart (2240 slots x 2048 = 4,587,520 <= 4,702,208).
  ushort* WoT   = (ushort*)d_ws;                          //   802,816
  ushort* WqkvT = WoT   + (size_t)HID * HID;              // 1,032,192
  ushort* Ah    = WqkvT + (size_t)QKV_COLS * HID;         // 3,670,016
  ushort* Qb    = Ah    + (size_t)4096 * HID;             // 3,670,016
  ushort* Kb    = Qb    + (size_t)BB * HQ  * NN * DD;     //   524,288
  ushort* Vtb   = Kb    + (size_t)BB * HKV * NN * DD;     //   524,288
  ushort* Ob    = Vtb   + (size_t)BB * HKV * NN * DD;     // 3,670,016
  float2* tab   = (float2*)(Ob + (size_t)4096 * HID);     // 4096*32 float2
  float*  biasQ = (float*)(tab + (size_t)4096 * 32);      // 1152
  float*  mpart = biasQ + QKV_COLS;                       // 2240*32 = 71,680
  float*  lpart = mpart + (size_t)2240 * 32;
  ushort* Opart = WqkvT;                                  // overlay (dead region)

  prep_kernel<<<dim3(5893), 256, 0, stream>>>(hid, pos, qw, kw, vw, ow, qb, kb, vb,
                                              Ah, WqkvT, WoT, tab, biasQ);
  gemm_qkv_rope<<<dim3(9, 64), 256, 0, stream>>>(Ah, WqkvT, biasQ, tab, Qb, Kb, Vtb);
  attn_kernel<<<dim3(108, HQ, BB), 64, 0, stream>>>(Qb, Kb, Vtb, Ob, Opart, mpart, lpart);
  attn_reduce_kernel<<<dim3(36, HQ, BB), 256, 0, stream>>>(Opart, mpart, lpart, Ob);
  gemm_o<<<dim3(HID / 128, 64), 256, 0, stream>>>(Ob, WoT, outp);
}